// Round 9
// baseline (86.268 us; speedup 1.0000x reference)
//
#include <hip/hip_runtime.h>
#include <math.h>

// Problem constants
#define F_ 126
#define NPG 128              // nodes per graph
#define EPG 2048             // edges per graph
#define ET 524288            // total edges
#define NEG_SLOPE 0.2f

typedef short bf16x8 __attribute__((ext_vector_type(8)));
typedef float f32x4 __attribute__((ext_vector_type(4)));

__device__ __forceinline__ float bf2f(unsigned short u) {
  return __uint_as_float(((unsigned)u) << 16);
}
__device__ __forceinline__ unsigned short f2bf(float f) {
  unsigned x = __float_as_uint(f);
  unsigned r = x + 0x7fffu + ((x >> 16) & 1u);   // RNE
  return (unsigned short)(r >> 16);
}
#define SW(r)  (((r) & 7) << 4)    // bf16-row swizzle (16B granule)
#define SWB(d) (((d) & 15) << 3)   // byte-matrix swizzle (8B granule)

// ---------------- K0: WcT[type][c][k] = (W_type @ W_gat)[k][c] (bf16) + zero out ----------
__global__ __launch_bounds__(256) void k0_wct(const float* __restrict__ Wf,
                                              const float* __restrict__ Wu,
                                              const float* __restrict__ Wi,
                                              const float* __restrict__ Wg,
                                              unsigned short* __restrict__ wct,
                                              float* __restrict__ out) {
  // zero the output accumulator (k2f atomically accumulates; stream order guarantees this runs first)
  for (int i = blockIdx.x * 256 + threadIdx.x; i < 256 * F_; i += 96 * 256) out[i] = 0.f;

  const int blk = blockIdx.x;
  const int type = blk >> 5;
  const int cg = (blk & 31) * 8;
  const float* Wx = (type == 0) ? Wf : ((type == 1) ? Wu : Wi);
  __shared__ float gT[8][256];
#pragma unroll
  for (int cc = 0; cc < 8; ++cc) gT[cc][threadIdx.x] = Wg[threadIdx.x * 256 + cg + cc];
  __syncthreads();
  const int k = threadIdx.x;
  const float4* wrow = reinterpret_cast<const float4*>(Wx + k * 256);
  float acc[8] = {};
  for (int j4 = 0; j4 < 64; ++j4) {
    float4 v = wrow[j4];
#pragma unroll
    for (int cc = 0; cc < 8; ++cc) {
      float4 gv = *reinterpret_cast<const float4*>(&gT[cc][j4 * 4]);
      acc[cc] += v.x * gv.x + v.y * gv.y + v.z * gv.z + v.w * gv.w;
    }
  }
#pragma unroll
  for (int cc = 0; cc < 8; ++cc)
    wct[((size_t)type * 256 + cg + cc) * 256 + k] = f2bf(acc[cc]);
}

// ---------------- K2F: per-(graph, head-pair) block; 512 blocks, 2 blocks/CU --------------
// LDS (53.8 KB): hT bf16 [128 diml][128 src] (32K) | M uint8 [128 d][128 s] (16K)
//                asT/adT f32 [2][128] | asl/adl/wo f32 [128] | lpf f32 [128][2]
#define LDS_SZ 53760

__global__ __launch_bounds__(512, 4) void k2f(
    const int* __restrict__ fid, const int* __restrict__ userid, const int* __restrict__ itemid,
    const int* __restrict__ ei,
    const float* __restrict__ ftab, const float* __restrict__ utab, const float* __restrict__ itab,
    const unsigned short* __restrict__ wct,
    const float* __restrict__ a_src, const float* __restrict__ a_dst,
    const float* __restrict__ W_out, const float* __restrict__ b_out,
    float* __restrict__ out) {
  __shared__ __align__(16) char smem[LDS_SZ];
  const int g = blockIdx.x & 255;
  const int hpair = blockIdx.x >> 8;       // pair (g,0)/(g,1) lands on same XCD (256%8==0)
  const int tid = threadIdx.x;
  const int lane = tid & 63;
  const int wid = tid >> 6;                // 0..7
  const int rl = lane & 15;
  const int kg = lane >> 4;

  char* Ht  = smem;                        // 32768
  char* Mb  = smem + 32768;                // 16384
  float* asT = (float*)(smem + 49152);     // [2][128]
  float* adT = asT + 256;
  float* asl = adT + 256;                  // [128] this pair's a_src cols
  float* adl = asl + 128;
  float* wo  = adl + 128;
  float* lpf = wo + 128;                   // [128][2]

  // edges -> registers (4 per thread)
  int4 es = *(const int4*)(ei + (size_t)g * EPG + tid * 4);
  int4 ed = *(const int4*)(ei + (size_t)ET + (size_t)g * EPG + tid * 4);
  int se[4] = { es.x - g * NPG, es.y - g * NPG, es.z - g * NPG, es.w - g * NPG };
  int de[4] = { ed.x - g * NPG, ed.y - g * NPG, ed.z - g * NPG, ed.w - g * NPG };

  // stage + zero
  if (tid < 128)       asl[tid] = a_src[hpair * 128 + tid];
  else if (tid < 256)  adl[tid - 128] = a_dst[hpair * 128 + tid - 128];
  else if (tid < 384)  wo[tid - 256] = W_out[hpair * 128 + tid - 256];
  else if (tid < 392) { int u = tid - 384; float* p = (u < 4) ? asT : adT;
                        p[((u & 2) >> 1) * 128 + 126 + (u & 1)] = 0.f; }
  { uint4 z = { 0, 0, 0, 0 };
    *(uint4*)(Mb + tid * 32) = z; *(uint4*)(Mb + tid * 32 + 16) = z; }
  const float bo = b_out[0];
  __syncthreads();                                           // b0

  // scatter edge multiplicity into byte-packed M (atomics drain under GEMM1/GEMV)
#pragma unroll
  for (int j = 0; j < 4; ++j) {
    int bofs = (de[j] * 128 + se[j]) ^ SWB(de[j]);
    atomicAdd((int*)(Mb + (bofs & ~3)), 1 << ((bofs & 3) * 8));
  }

  // ---- GEMV: user/item h rows for this pair's 128 dims (threads 0..255) ----
  if (tid < 256) {
    const int r2 = 126 + (tid >> 7);
    const int dml = tid & 127;
    const float* er = (tid < 128) ? (utab + (size_t)userid[g] * 256)
                                  : (itab + (size_t)itemid[g] * 256);
    const unsigned short* wr = wct + (size_t)(1 + (tid >> 7)) * 65536
                                   + (size_t)(hpair * 128 + dml) * 256;
    float hv = 0.f;
#pragma unroll 4
    for (int j = 0; j < 32; ++j) {
      uint4 w8 = *(const uint4*)(wr + j * 8);
      float4 e0 = *(const float4*)(er + j * 8);
      float4 e1 = *(const float4*)(er + j * 8 + 4);
      const unsigned short* wp = (const unsigned short*)&w8;
      hv += e0.x * bf2f(wp[0]) + e0.y * bf2f(wp[1]) + e0.z * bf2f(wp[2]) + e0.w * bf2f(wp[3]);
      hv += e1.x * bf2f(wp[4]) + e1.y * bf2f(wp[5]) + e1.z * bf2f(wp[6]) + e1.w * bf2f(wp[7]);
    }
    *(unsigned short*)(Ht + ((dml * 256 + r2 * 2) ^ SW(dml))) = f2bf(hv);
    int lh = dml >> 6;
    atomicAdd(&asT[lh * 128 + r2], hv * asl[dml]);
    atomicAdd(&adT[lh * 128 + r2], hv * adl[dml]);
  }

  // ---- GEMM1: h[128 rows][128 dims] = emb @ wct-cols; wave = 16 rows x 128 dims ----
  const int arow = wid * 16 + rl;
  const float* rp;
  if (arow < F_)       rp = ftab + (size_t)fid[g * F_ + arow] * 256;
  else if (arow == F_) rp = utab + (size_t)userid[g] * 256;   // placeholder; GEMV overwrites
  else                 rp = itab + (size_t)itemid[g] * 256;
  const unsigned short* bp0 = wct + (size_t)(hpair * 128 + rl) * 256;

  f32x4 acc[8] = {};
#pragma unroll
  for (int ks = 0; ks < 8; ++ks) {
    bf16x8 af;
    {
      float4 v0 = *(const float4*)(rp + ks * 32 + kg * 8);
      float4 v1 = *(const float4*)(rp + ks * 32 + kg * 8 + 4);
      af[0] = (short)f2bf(v0.x); af[1] = (short)f2bf(v0.y);
      af[2] = (short)f2bf(v0.z); af[3] = (short)f2bf(v0.w);
      af[4] = (short)f2bf(v1.x); af[5] = (short)f2bf(v1.y);
      af[6] = (short)f2bf(v1.z); af[7] = (short)f2bf(v1.w);
    }
#pragma unroll
    for (int nf = 0; nf < 8; ++nf) {
      bf16x8 bfv = *(const bf16x8*)(bp0 + (size_t)nf * 4096 + ks * 32 + kg * 8);
      acc[nf] = __builtin_amdgcn_mfma_f32_16x16x32_bf16(af, bfv, acc[nf], 0, 0, 0);
    }
  }

  // ---- as/ad from f32 acc (per local head) ----
#pragma unroll
  for (int i = 0; i < 4; ++i) {
    float ps0 = 0.f, ps1 = 0.f, pd0 = 0.f, pd1 = 0.f;
#pragma unroll
    for (int nf = 0; nf < 4; ++nf) {
      float v = acc[nf][i];
      ps0 += v * asl[nf * 16 + rl]; pd0 += v * adl[nf * 16 + rl];
      float v2 = acc[nf + 4][i];
      ps1 += v2 * asl[64 + nf * 16 + rl]; pd1 += v2 * adl[64 + nf * 16 + rl];
    }
#pragma unroll
    for (int d2 = 1; d2 < 16; d2 <<= 1) {
      ps0 += __shfl_xor(ps0, d2); ps1 += __shfl_xor(ps1, d2);
      pd0 += __shfl_xor(pd0, d2); pd1 += __shfl_xor(pd1, d2);
    }
    int row = wid * 16 + kg * 4 + i;
    if (rl == 0 && row < F_) {
      asT[row] = ps0; asT[128 + row] = ps1;
      adT[row] = pd0; adT[128 + row] = pd1;
    }
  }

  // ---- transpose-write hT[diml][src] ----
  {
    const int srcb = wid * 16 + kg * 4;
#pragma unroll
    for (int nf = 0; nf < 8; ++nf) {
      int dml = nf * 16 + rl;
      unsigned lo = (unsigned)f2bf(acc[nf][0]) | ((unsigned)f2bf(acc[nf][1]) << 16);
      unsigned hi = (unsigned)f2bf(acc[nf][2]) | ((unsigned)f2bf(acc[nf][3]) << 16);
      int bofs = (dml * 256 + srcb * 2) ^ SW(dml);
      if (srcb < 124) { uint2 u = { lo, hi }; *(uint2*)(Ht + bofs) = u; }
      else            { *(unsigned*)(Ht + bofs) = lo; }   // src 124,125; 126/127 via GEMV
    }
  }
  __syncthreads();                                           // b1: M, hT, asT, adT ready

  // ---- 2 local head passes, barrier-free: A in-reg from M,asT,adT; GEMM2 + fused epilogue
  float lp[2][4] = {};
  const int mb2 = (wid & 3) * 32;
  const int nb2 = (wid >> 2) * 32;     // within-head dim base

  for (int lh = 0; lh < 2; ++lh) {
    const float adv0 = adT[lh * 128 + mb2 + rl];
    const float adv1 = adT[lh * 128 + mb2 + 16 + rl];
    float denp0 = 0.f, denp1 = 0.f;
    f32x4 acc2[2][2] = {};
#pragma unroll
    for (int ks = 0; ks < 4; ++ks) {
      f32x4 as0 = *(const f32x4*)(&asT[lh * 128 + ks * 32 + kg * 8]);
      f32x4 as1 = *(const f32x4*)(&asT[lh * 128 + ks * 32 + kg * 8 + 4]);
      bf16x8 b2[2];
#pragma unroll
      for (int nf = 0; nf < 2; ++nf) {
        int dml = lh * 64 + nb2 + nf * 16 + rl;
        b2[nf] = *(const bf16x8*)(Ht + ((dml * 256 + ks * 64 + kg * 16) ^ SW(dml)));
      }
#pragma unroll
      for (int mf = 0; mf < 2; ++mf) {
        int d = mb2 + mf * 16 + rl;
        uint2 m8 = *(const uint2*)(Mb + ((d * 128 + ks * 32 + kg * 8) ^ SWB(d)));
        float adv = mf ? adv1 : adv0;
        bf16x8 a2;
        float dsum = 0.f;
#pragma unroll
        for (int j = 0; j < 8; ++j) {
          int mv = ((j < 4) ? (m8.x >> (8 * j)) : (m8.y >> (8 * (j - 4)))) & 255;
          float e = ((j < 4) ? as0[j] : as1[j - 4]) + adv;
          e = (e < 0.f) ? NEG_SLOPE * e : e;
          float w = __expf(e) * (float)mv;
          dsum += w;
          a2[j] = (short)f2bf(w);
        }
        if (mf) denp1 += dsum; else denp0 += dsum;
#pragma unroll
        for (int nf = 0; nf < 2; ++nf)
          acc2[mf][nf] = __builtin_amdgcn_mfma_f32_16x16x32_bf16(a2, b2[nf], acc2[mf][nf], 0, 0, 0);
      }
    }
    denp0 += __shfl_xor(denp0, 16); denp0 += __shfl_xor(denp0, 32);
    denp1 += __shfl_xor(denp1, 16); denp1 += __shfl_xor(denp1, 32);
#pragma unroll
    for (int mf = 0; mf < 2; ++mf) {
#pragma unroll
      for (int i = 0; i < 4; ++i) {
        float dni = __shfl(mf ? denp1 : denp0, kg * 4 + i);
        float rd = __builtin_amdgcn_rcpf(dni + 1e-16f);
#pragma unroll
        for (int nf = 0; nf < 2; ++nf) {
          float v = acc2[mf][nf][i] * rd;
          v = (v > 0.f) ? v : (__expf(v) - 1.f);
          lp[mf][i] += v * wo[lh * 64 + nb2 + nf * 16 + rl];
        }
      }
    }
  }

  // ---- readout reduce + global accumulate (exactly 2 commutative atomics per element) ----
#pragma unroll
  for (int mf = 0; mf < 2; ++mf) {
#pragma unroll
    for (int i = 0; i < 4; ++i) {
      float v = lp[mf][i];
#pragma unroll
      for (int d2 = 1; d2 < 16; d2 <<= 1) v += __shfl_xor(v, d2);
      if (rl == 0) lpf[(mb2 + mf * 16 + kg * 4 + i) * 2 + (wid >> 2)] = v;
    }
  }
  __syncthreads();                                           // b2
  if (tid < F_) {
    float v = lpf[tid * 2] + lpf[tid * 2 + 1];
    if (hpair == 0) v += bo;
    atomicAdd(&out[(size_t)g * F_ + tid], v);
  }
}

extern "C" void kernel_launch(void* const* d_in, const int* in_sizes, int n_in,
                              void* d_out, int out_size, void* d_ws, size_t ws_size,
                              hipStream_t stream) {
  const int* fid      = (const int*)d_in[0];
  const int* userid   = (const int*)d_in[1];
  const int* itemid   = (const int*)d_in[2];
  const int* ei       = (const int*)d_in[3];
  const float* ftab   = (const float*)d_in[4];
  const float* utab   = (const float*)d_in[5];
  const float* itab   = (const float*)d_in[6];
  const float* Wf     = (const float*)d_in[7];
  const float* Wu     = (const float*)d_in[8];
  const float* Wi     = (const float*)d_in[9];
  const float* Wg     = (const float*)d_in[10];
  const float* a_src  = (const float*)d_in[11];
  const float* a_dst  = (const float*)d_in[12];
  const float* W_out  = (const float*)d_in[13];
  const float* b_out  = (const float*)d_in[14];
  float* out = (float*)d_out;

  unsigned short* ws_wct = (unsigned short*)d_ws;   // 384 KB

  hipLaunchKernelGGL(k0_wct, dim3(96), dim3(256), 0, stream, Wf, Wu, Wi, Wg, ws_wct, out);
  hipLaunchKernelGGL(k2f, dim3(512), dim3(512), 0, stream,
                     fid, userid, itemid, ei, ftab, utab, itab, ws_wct,
                     a_src, a_dst, W_out, b_out, out);
}

// Round 10
// 70.107 us; speedup vs baseline: 1.2305x; 1.2305x over previous
//
#include <hip/hip_runtime.h>
#include <math.h>

// Problem constants
#define F_ 126
#define NPG 128              // nodes per graph
#define EPG 2048             // edges per graph
#define ET 524288            // total edges
#define NEG_SLOPE 0.2f

typedef short bf16x8 __attribute__((ext_vector_type(8)));
typedef float f32x4 __attribute__((ext_vector_type(4)));

__device__ __forceinline__ float bf2f(unsigned short u) {
  return __uint_as_float(((unsigned)u) << 16);
}
__device__ __forceinline__ unsigned short f2bf(float f) {
  unsigned x = __float_as_uint(f);
  unsigned r = x + 0x7fffu + ((x >> 16) & 1u);   // RNE
  return (unsigned short)(r >> 16);
}
// single-instruction packed f32x2 -> bf16x2 (RNE), gfx950
__device__ __forceinline__ unsigned cvtpk(float lo, float hi) {
  unsigned r;
  asm("v_cvt_pk_bf16_f32 %0, %1, %2" : "=v"(r) : "v"(lo), "v"(hi));
  return r;
}
union bfpack { unsigned u[4]; bf16x8 v; };

#define SW(r)  (((r) & 7) << 4)    // bf16-row swizzle (16B granule)
#define SWB(d) (((d) & 15) << 3)   // byte-matrix swizzle (8B granule)

// ---------------- K0: WcT[type][c][k] = (W_type @ W_gat)[k][c]  (bf16) -------------------
__global__ __launch_bounds__(256) void k0_wct(const float* __restrict__ Wf,
                                              const float* __restrict__ Wu,
                                              const float* __restrict__ Wi,
                                              const float* __restrict__ Wg,
                                              unsigned short* __restrict__ wct) {
  const int blk = blockIdx.x;
  const int type = blk >> 5;
  const int cg = (blk & 31) * 8;
  const float* Wx = (type == 0) ? Wf : ((type == 1) ? Wu : Wi);
  __shared__ float gT[8][256];
#pragma unroll
  for (int cc = 0; cc < 8; ++cc) gT[cc][threadIdx.x] = Wg[threadIdx.x * 256 + cg + cc];
  __syncthreads();
  const int k = threadIdx.x;
  const float4* wrow = reinterpret_cast<const float4*>(Wx + k * 256);
  float acc[8] = {};
  for (int j4 = 0; j4 < 64; ++j4) {
    float4 v = wrow[j4];
#pragma unroll
    for (int cc = 0; cc < 8; ++cc) {
      float4 gv = *reinterpret_cast<const float4*>(&gT[cc][j4 * 4]);
      acc[cc] += v.x * gv.x + v.y * gv.y + v.z * gv.z + v.w * gv.w;
    }
  }
#pragma unroll
  for (int cc = 0; cc < 8; ++cc)
    wct[((size_t)type * 256 + cg + cc) * 256 + k] = f2bf(acc[cc]);
}

// ---------------- K2F: fused per-graph kernel (1024 thr, 1 block/graph) -------------------
// LDS 94208 B: hT bf16 [256 dim][128 src] | M u8 [128 d][128 s] (SWB) |
//              EsT/FsT/EdT/FdT f32 [4 hd][128 node] | asl/adl/wo f32[256] | lpf f32[128][2]
#define OFF_HT   0
#define OFF_M    65536
#define OFF_ES   81920
#define OFF_FS   83968
#define OFF_ED   86016
#define OFF_FD   88064
#define OFF_ASL  90112
#define OFF_ADL  91136
#define OFF_WO   92160
#define OFF_LP   93184
#define LDS_SZ   94208

__global__ __launch_bounds__(1024, 1) void k2f(
    const int* __restrict__ fid, const int* __restrict__ userid, const int* __restrict__ itemid,
    const int* __restrict__ ei,
    const float* __restrict__ ftab, const float* __restrict__ utab, const float* __restrict__ itab,
    const unsigned short* __restrict__ wct,
    const float* __restrict__ a_src, const float* __restrict__ a_dst,
    const float* __restrict__ W_out, const float* __restrict__ b_out,
    float* __restrict__ out) {
  __shared__ __align__(16) char smem[LDS_SZ];
  const int g = blockIdx.x;
  const int tid = threadIdx.x;
  const int lane = tid & 63;
  const int wid = tid >> 6;          // 0..15
  const int rl = lane & 15;
  const int kg = lane >> 4;

  char* Ht = smem + OFF_HT;
  char* Mb = smem + OFF_M;
  float* EsT = (float*)(smem + OFF_ES);   // [hd*128 + node]
  float* FsT = (float*)(smem + OFF_FS);
  float* EdT = (float*)(smem + OFF_ED);
  float* FdT = (float*)(smem + OFF_FD);
  float* asl = (float*)(smem + OFF_ASL);
  float* adl = (float*)(smem + OFF_ADL);
  float* wo  = (float*)(smem + OFF_WO);
  float* lpf = (float*)(smem + OFF_LP);

  // edges -> registers (2 per thread)
  int2 es = *(const int2*)(ei + (size_t)g * EPG + tid * 2);
  int2 ed = *(const int2*)(ei + (size_t)ET + (size_t)g * EPG + tid * 2);
  int se[2] = { es.x - g * NPG, es.y - g * NPG };
  int de[2] = { ed.x - g * NPG, ed.y - g * NPG };

  // stage + zero M bytes
  if (tid < 256)      { asl[tid] = a_src[tid]; wo[tid] = W_out[tid]; }
  else if (tid < 512) { adl[tid - 256] = a_dst[tid - 256]; }
  { uint4 z = { 0, 0, 0, 0 }; *(uint4*)(Mb + tid * 16) = z; }
  const float bo = b_out[0];
  __syncthreads();                                           // b0

  // scatter edge multiplicity into byte-packed M (drains under GEMM1)
#pragma unroll
  for (int j = 0; j < 2; ++j) {
    int bofs = (de[j] * 128 + se[j]) ^ SWB(de[j]);
    atomicAdd((int*)(Mb + (bofs & ~3)), 1 << ((bofs & 3) * 8));
  }

  // ---- GEMM1: h = emb @ Wc(type0); wave tile 32 rows x 64 dims (head nq) ----
  const int mh = wid & 3, nq = wid >> 2;
  f32x4 acc[2][4] = {};
  const float* rp[2];
#pragma unroll
  for (int mf = 0; mf < 2; ++mf) {
    int row = mh * 32 + mf * 16 + rl;
    if (row < F_)       rp[mf] = ftab + (size_t)fid[g * F_ + row] * 256;
    else if (row == F_) rp[mf] = utab + (size_t)userid[g] * 256;  // placeholder; GEMV fixes
    else                rp[mf] = itab + (size_t)itemid[g] * 256;
  }
  const unsigned short* bp[4];
#pragma unroll
  for (int nf = 0; nf < 4; ++nf)
    bp[nf] = wct + (size_t)(nq * 64 + nf * 16 + rl) * 256;

#pragma unroll
  for (int ks = 0; ks < 8; ++ks) {
    bf16x8 af[2], bfv[4];
#pragma unroll
    for (int mf = 0; mf < 2; ++mf) {
      float4 v0 = *(const float4*)(rp[mf] + ks * 32 + kg * 8);
      float4 v1 = *(const float4*)(rp[mf] + ks * 32 + kg * 8 + 4);
      bfpack p;
      p.u[0] = cvtpk(v0.x, v0.y); p.u[1] = cvtpk(v0.z, v0.w);
      p.u[2] = cvtpk(v1.x, v1.y); p.u[3] = cvtpk(v1.z, v1.w);
      af[mf] = p.v;
    }
#pragma unroll
    for (int nf = 0; nf < 4; ++nf)
      bfv[nf] = *(const bf16x8*)(bp[nf] + ks * 32 + kg * 8);
#pragma unroll
    for (int mf = 0; mf < 2; ++mf)
#pragma unroll
      for (int nf = 0; nf < 4; ++nf)
        acc[mf][nf] = __builtin_amdgcn_mfma_f32_16x16x32_bf16(af[mf], bfv[nf], acc[mf][nf], 0, 0, 0);
  }

  // ---- as/ad reduce -> exp tables (head = nq) ----
  {
    float asv[4], adv[4];
#pragma unroll
    for (int nf = 0; nf < 4; ++nf) {
      asv[nf] = asl[nq * 64 + nf * 16 + rl];
      adv[nf] = adl[nq * 64 + nf * 16 + rl];
    }
#pragma unroll
    for (int mf = 0; mf < 2; ++mf) {
#pragma unroll
      for (int i = 0; i < 4; ++i) {
        float ps = 0.f, pd = 0.f;
#pragma unroll
        for (int nf = 0; nf < 4; ++nf) { float v = acc[mf][nf][i]; ps += v * asv[nf]; pd += v * adv[nf]; }
#pragma unroll
        for (int d2 = 1; d2 < 16; d2 <<= 1) { ps += __shfl_xor(ps, d2); pd += __shfl_xor(pd, d2); }
        int row = mh * 32 + mf * 16 + kg * 4 + i;
        if (rl == 0 && row < F_) {
          EsT[nq * 128 + row] = __expf(ps);
          FsT[nq * 128 + row] = __expf(NEG_SLOPE * ps);
          EdT[nq * 128 + row] = __expf(pd);
          FdT[nq * 128 + row] = __expf(NEG_SLOPE * pd);
        }
      }
    }
  }

  // ---- transpose-write hT[dim][src] (cvt_pk) ----
  {
#pragma unroll
    for (int mf = 0; mf < 2; ++mf) {
      int srcb = mh * 32 + mf * 16 + kg * 4;
#pragma unroll
      for (int nf = 0; nf < 4; ++nf) {
        int dim = nq * 64 + nf * 16 + rl;
        unsigned lo = cvtpk(acc[mf][nf][0], acc[mf][nf][1]);
        unsigned hi = cvtpk(acc[mf][nf][2], acc[mf][nf][3]);
        int bofs = (dim * 256 + srcb * 2) ^ SW(dim);
        if (srcb < 124) { uint2 u = { lo, hi }; *(uint2*)(Ht + bofs) = u; }
        else            { *(unsigned*)(Ht + bofs) = lo; }   // src 124,125; 126/127 via GEMV
      }
    }
  }

  // ---- GEMV: user/item source rows (threads 0..511) ----
  if (tid < 512) {
    const int r2 = F_ + (tid >> 8);
    const int c2 = tid & 255;
    const float* er = (tid < 256) ? (utab + (size_t)userid[g] * 256)
                                  : (itab + (size_t)itemid[g] * 256);
    const uint4* wr = (const uint4*)(wct + (size_t)(1 + (tid >> 8)) * 65536 + (size_t)c2 * 256);
    const float4* e4 = (const float4*)er;
    float hv = 0.f;
#pragma unroll 4
    for (int j = 0; j < 32; ++j) {
      uint4 w8 = wr[j];
      float4 e0 = e4[2 * j], e1 = e4[2 * j + 1];
      const unsigned short* wp = (const unsigned short*)&w8;
      hv += e0.x * bf2f(wp[0]) + e0.y * bf2f(wp[1]) + e0.z * bf2f(wp[2]) + e0.w * bf2f(wp[3]);
      hv += e1.x * bf2f(wp[4]) + e1.y * bf2f(wp[5]) + e1.z * bf2f(wp[6]) + e1.w * bf2f(wp[7]);
    }
    float gps = hv * asl[c2];
    float gpd = hv * adl[c2];
#pragma unroll
    for (int d2 = 32; d2 >= 1; d2 >>= 1) { gps += __shfl_xor(gps, d2); gpd += __shfl_xor(gpd, d2); }
    if (lane == 0) {
      int h2 = wid & 3;
      EsT[h2 * 128 + r2] = __expf(gps);
      FsT[h2 * 128 + r2] = __expf(NEG_SLOPE * gps);
      EdT[h2 * 128 + r2] = __expf(gpd);
      FdT[h2 * 128 + r2] = __expf(NEG_SLOPE * gpd);
    }
    *(unsigned short*)(Ht + ((c2 * 256 + r2 * 2) ^ SW(c2))) = f2bf(hv);
  }
  __syncthreads();                                           // b1: M, hT, exp tables ready

  // ---- 4 head passes, barrier-free; A[d][s] = M[d][s] * max(Es[s]Ed[d], Fs[s]Fd[d]) ----
  float lp[4] = {};
  const int m2 = (wid & 7) * 16, n2 = (wid >> 3) * 32;
  const int drow = m2 + rl;

  for (int hd = 0; hd < 4; ++hd) {
    const float Edv = EdT[hd * 128 + drow];
    const float Fdv = FdT[hd * 128 + drow];
    float denp = 0.f;
    f32x4 acc2[2] = {};
#pragma unroll
    for (int ks = 0; ks < 4; ++ks) {
      uint2 m8 = *(const uint2*)(Mb + ((drow * 128 + ks * 32 + kg * 8) ^ SWB(drow)));
      f32x4 Es0 = *(const f32x4*)(&EsT[hd * 128 + ks * 32 + kg * 8]);
      f32x4 Es1 = *(const f32x4*)(&EsT[hd * 128 + ks * 32 + kg * 8 + 4]);
      f32x4 Fs0 = *(const f32x4*)(&FsT[hd * 128 + ks * 32 + kg * 8]);
      f32x4 Fs1 = *(const f32x4*)(&FsT[hd * 128 + ks * 32 + kg * 8 + 4]);
      float av[8];
#pragma unroll
      for (int j = 0; j < 8; ++j) {
        float mv = (float)(int)((j < 4 ? (m8.x >> (8 * j)) : (m8.y >> (8 * (j - 4)))) & 255u);
        float w = fmaxf(((j < 4) ? Es0[j] : Es1[j - 4]) * Edv,
                        ((j < 4) ? Fs0[j] : Fs1[j - 4]) * Fdv) * mv;
        av[j] = w;
        denp += w;
      }
      bfpack a2;
      a2.u[0] = cvtpk(av[0], av[1]); a2.u[1] = cvtpk(av[2], av[3]);
      a2.u[2] = cvtpk(av[4], av[5]); a2.u[3] = cvtpk(av[6], av[7]);
      bf16x8 b2[2];
#pragma unroll
      for (int nf = 0; nf < 2; ++nf) {
        int dim = hd * 64 + n2 + nf * 16 + rl;
        b2[nf] = *(const bf16x8*)(Ht + ((dim * 256 + ks * 64 + kg * 16) ^ SW(dim)));
      }
#pragma unroll
      for (int nf = 0; nf < 2; ++nf)
        acc2[nf] = __builtin_amdgcn_mfma_f32_16x16x32_bf16(a2.v, b2[nf], acc2[nf], 0, 0, 0);
    }
    denp += __shfl_xor(denp, 16);
    denp += __shfl_xor(denp, 32);
#pragma unroll
    for (int i = 0; i < 4; ++i) {
      float dni = __shfl(denp, kg * 4 + i);        // lane with rl == kg*4+i holds row's den
      float rd = __builtin_amdgcn_rcpf(dni + 1e-16f);
#pragma unroll
      for (int nf = 0; nf < 2; ++nf) {
        float v = acc2[nf][i] * rd;
        v = (v > 0.f) ? v : (__expf(v) - 1.f);
        lp[i] += v * wo[hd * 64 + n2 + nf * 16 + rl];
      }
    }
  }

  // ---- readout reduce + direct store ----
#pragma unroll
  for (int i = 0; i < 4; ++i) {
    float v = lp[i];
#pragma unroll
    for (int d2 = 1; d2 < 16; d2 <<= 1) v += __shfl_xor(v, d2);
    if (rl == 0) lpf[(m2 + kg * 4 + i) * 2 + (wid >> 3)] = v;
  }
  __syncthreads();                                           // b2
  if (tid < F_) out[(size_t)g * F_ + tid] = lpf[tid * 2] + lpf[tid * 2 + 1] + bo;
}

extern "C" void kernel_launch(void* const* d_in, const int* in_sizes, int n_in,
                              void* d_out, int out_size, void* d_ws, size_t ws_size,
                              hipStream_t stream) {
  const int* fid      = (const int*)d_in[0];
  const int* userid   = (const int*)d_in[1];
  const int* itemid   = (const int*)d_in[2];
  const int* ei       = (const int*)d_in[3];
  const float* ftab   = (const float*)d_in[4];
  const float* utab   = (const float*)d_in[5];
  const float* itab   = (const float*)d_in[6];
  const float* Wf     = (const float*)d_in[7];
  const float* Wu     = (const float*)d_in[8];
  const float* Wi     = (const float*)d_in[9];
  const float* Wg     = (const float*)d_in[10];
  const float* a_src  = (const float*)d_in[11];
  const float* a_dst  = (const float*)d_in[12];
  const float* W_out  = (const float*)d_in[13];
  const float* b_out  = (const float*)d_in[14];
  float* out = (float*)d_out;

  unsigned short* ws_wct = (unsigned short*)d_ws;   // 384 KB

  hipLaunchKernelGGL(k0_wct, dim3(96), dim3(256), 0, stream, Wf, Wu, Wi, Wg, ws_wct);
  hipLaunchKernelGGL(k2f, dim3(256), dim3(1024), 0, stream,
                     fid, userid, itemid, ei, ftab, utab, itab, ws_wct,
                     a_src, a_dst, W_out, b_out, out);
}